// Round 2
// baseline (418.639 us; speedup 1.0000x reference)
//
#include <hip/hip_runtime.h>
#include <cstdio>

// VQ nearest-codebook, round 6.
// Restructured vq_main: A (queries) held entirely in registers (32 rows x
// K=512 fp16 = 128 VGPR/lane), codebook streamed through LDS in 16
// double-buffered 64-code chunks (single barrier per chunk; prefetch drains
// at next iteration's implicit vmcnt(0)). Reads x fp32 directly (convx
// eliminated); computes global argmin in-block (reduce eliminated).
// Staged bytes per CU: 2 MB -> 1.25 MB; A re-reads eliminated.
// vq_refine batched 8 queries per cbT sweep (8x fewer global reads).
// fp16 stage-1 + TAU 0.05 + exact fp64 refine of flagged + gather.

typedef float f32x4 __attribute__((ext_vector_type(4)));
typedef _Float16 half8 __attribute__((ext_vector_type(8)));

#define KDIM 512
#define NCODES 1024
#define NQ 65536
#define TAU_S 0.05f   // fp16 dot err sigma ~0.009; 0.05 ~ 5.5 sigma (passed R3-R5, absmax 0)

// ---- workspace layout (bytes) ----
#define WS_CBH   0ull                         // fp16 cb [1024][512]   1048576
#define WS_C2H   1048576ull                   // float 0.5||c||^2 [1024]  4096
#define WS_C2D   1052672ull                   // double 0.5||c||^2 [1024] 8192
#define WS_CBT   1060864ull                   // fp32 cbT [512][1024]  2097152
#define WS_IDX   3158016ull                   // int [65536]            262144
#define WS_LIST  3420160ull                   // int [65536]            262144
#define WS_CTR   3682304ull                   // int
#define WS_NEED  (WS_CTR + 4ull)

__device__ __forceinline__ unsigned short f2h(float f) {
  _Float16 h = (_Float16)f;                   // RNE
  return __builtin_bit_cast(unsigned short, h);
}

__device__ __forceinline__ void async16(const void* g, void* l) {
  __builtin_amdgcn_global_load_lds(
      (const __attribute__((address_space(1))) void*)g,
      (__attribute__((address_space(3))) void*)l, 16, 0, 0);
}

// ---------------- prep: codebook -> fp16 row-major + 0.5||c||^2 ----------------
__global__ __launch_bounds__(256) void vq_prep(const float* __restrict__ cb,
                                               unsigned short* __restrict__ cbh,
                                               float* __restrict__ c2h,
                                               double* __restrict__ c2d) {
  int lane = threadIdx.x & 63;
  int row = blockIdx.x * 4 + (threadIdx.x >> 6);
  const float4* src = (const float4*)(cb + (size_t)row * KDIM);
  float4 u = src[lane * 2], v = src[lane * 2 + 1];
  double p = (double)u.x * u.x + (double)u.y * u.y + (double)u.z * u.z + (double)u.w * u.w +
             (double)v.x * v.x + (double)v.y * v.y + (double)v.z * v.z + (double)v.w * v.w;
#pragma unroll
  for (int m = 1; m < 64; m <<= 1) p += __shfl_xor(p, m);
  if (lane == 0) { c2h[row] = (float)(0.5 * p); c2d[row] = 0.5 * p; }
  unsigned r0 = f2h(u.x) | ((unsigned)f2h(u.y) << 16);
  unsigned r1 = f2h(u.z) | ((unsigned)f2h(u.w) << 16);
  unsigned r2 = f2h(v.x) | ((unsigned)f2h(v.y) << 16);
  unsigned r3 = f2h(v.z) | ((unsigned)f2h(v.w) << 16);
  *(int4*)(cbh + (size_t)row * KDIM + lane * 8) = make_int4((int)r0, (int)r1, (int)r2, (int)r3);
}

// ---------------- main: A-in-registers, codebook streamed via LDS ----------------
// grid 256 x 512 thr (8 waves). Wave wv owns 32 query rows (full K in regs).
// LDS: Bs[2][64 codes][512 halfs] = 128 KB dbuf + c2s[1024] floats = 4 KB.
// Chunk loop (16 x 64 codes): single __syncthreads per chunk; stage(ch+1)
// issued right after the barrier into the non-active buffer, drains at the
// NEXT barrier's implicit vmcnt(0) -> one full chunk (~2k cyc) of latency slack.
// LDS swizzle: 16B-granule index g (0..63 per 1024B row) stored at g^(row&7);
// row&7 == s for staging (rows wv*8+s) and == c&7 for reads -> uniform banks.
__global__ __launch_bounds__(512, 2) void vq_main(const float* __restrict__ x,
                                                  const unsigned short* __restrict__ cbh,
                                                  const float* __restrict__ c2h,
                                                  int* __restrict__ idx,
                                                  int* __restrict__ list,
                                                  int* __restrict__ counter) {
  __shared__ __align__(16) char pool[135168];
  float* c2s = (float*)(pool + 131072);

  const int tid = threadIdx.x;
  const int lane = tid & 63, wv = tid >> 6;
  const int c = lane & 15, q = lane >> 4;
  const int qbase = blockIdx.x * 256 + wv * 32;

#define STAGE(cc) do {                                                        \
    const unsigned short* _s = cbh + (size_t)(cc) * 32768 + wv * 4096;        \
    char* _d = pool + (((cc) & 1) * 65536) + wv * 8192 + lane * 16;           \
    _Pragma("unroll")                                                         \
    for (int s = 0; s < 8; ++s)                                               \
      async16(_s + s * 512 + ((lane ^ s) * 8), _d + s * 1024); } while (0)

  // ---- issue c2s + chunk-0 staging first (drained by A-load waits/barrier) ----
  if (wv < 4) async16(c2h + (wv * 64 + lane) * 4, pool + 131072 + wv * 1024 + lane * 16);
  STAGE(0);

  // ---- A-load: 32 rows x 512 dims fp32 -> fp16 fragments in registers ----
  // frag (rf,kf): lane holds x[qbase+rf*16+c][kf*32+q*8 .. +7]
  half8 a[2][16];
  {
    const float* xr0 = x + (size_t)(qbase + c) * KDIM + q * 8;
    const float* xr1 = xr0 + (size_t)16 * KDIM;
    float4 t0[8], t1[8];
    // prime group 0 (frags 0..3)
#pragma unroll
    for (int gj = 0; gj < 4; ++gj) {
      const float* p = xr0 + gj * 32;           // fi = gj: rf=0, kf=gj
      t0[gj * 2] = *(const float4*)p;
      t0[gj * 2 + 1] = *(const float4*)(p + 4);
    }
#pragma unroll
    for (int g = 0; g < 8; ++g) {
      if (g + 1 < 8) {
#pragma unroll
        for (int gj = 0; gj < 4; ++gj) {
          const int fi = (g + 1) * 4 + gj;
          const int rf = fi >> 4, kf = fi & 15;
          const float* p = (rf ? xr1 : xr0) + kf * 32;
          if ((g + 1) & 1) {
            t1[gj * 2] = *(const float4*)p; t1[gj * 2 + 1] = *(const float4*)(p + 4);
          } else {
            t0[gj * 2] = *(const float4*)p; t0[gj * 2 + 1] = *(const float4*)(p + 4);
          }
        }
      }
#pragma unroll
      for (int gj = 0; gj < 4; ++gj) {
        const int fi = g * 4 + gj;
        const int rf = fi >> 4, kf = fi & 15;
        float4 lo, hi;
        if (g & 1) { lo = t1[gj * 2]; hi = t1[gj * 2 + 1]; }
        else       { lo = t0[gj * 2]; hi = t0[gj * 2 + 1]; }
        half8 h;
        h[0] = (_Float16)lo.x; h[1] = (_Float16)lo.y;
        h[2] = (_Float16)lo.z; h[3] = (_Float16)lo.w;
        h[4] = (_Float16)hi.x; h[5] = (_Float16)hi.y;
        h[6] = (_Float16)hi.z; h[7] = (_Float16)hi.w;
        a[rf][kf] = h;
      }
      __builtin_amdgcn_sched_barrier(0);
    }
  }

  // ---- running (min1, min2, argmin) per (rf, r) ----
  float m1[2][4], m2[2][4];
  int mcx[2][4];
#pragma unroll
  for (int i = 0; i < 2; ++i)
#pragma unroll
    for (int r = 0; r < 4; ++r) { m1[i][r] = 1e30f; m2[i][r] = 1e30f; mcx[i][r] = 0; }

  const int crow = c * 512;
  const int m3 = c & 7;

#pragma unroll 1
  for (int ch = 0; ch < 16; ++ch) {
    __syncthreads();                 // implicit vmcnt(0): stage(ch) landed for all
    if (ch + 1 < 16) STAGE(ch + 1); // into buf[(ch+1)&1] (not read this iter)

    const unsigned short* B = (const unsigned short*)(pool + ((ch & 1) * 65536));
    f32x4 acc[2][4];
#pragma unroll
    for (int i = 0; i < 2; ++i)
#pragma unroll
      for (int j = 0; j < 4; ++j) acc[i][j] = (f32x4){0.f, 0.f, 0.f, 0.f};

#pragma unroll
    for (int kf = 0; kf < 16; ++kf) {
      half8 b[4];
      const int gg = (kf * 4 + q) ^ m3;
#pragma unroll
      for (int cf = 0; cf < 4; ++cf)
        b[cf] = *(const half8*)&B[cf * 8192 + crow + gg * 8];
#pragma unroll
      for (int i = 0; i < 2; ++i)
#pragma unroll
        for (int cf = 0; cf < 4; ++cf)
          acc[i][cf] = __builtin_amdgcn_mfma_f32_16x16x32_f16(a[i][kf], b[cf], acc[i][cf], 0, 0, 0);
    }
    // fold chunk scores into running min-state
#pragma unroll
    for (int cf = 0; cf < 4; ++cf) {
      const int col = ch * 64 + cf * 16 + c;
      const float c2v = c2s[col];
#pragma unroll
      for (int i = 0; i < 2; ++i)
#pragma unroll
        for (int r = 0; r < 4; ++r) {
          float sv = c2v - acc[i][cf][r];
          float hi = fmaxf(sv, m1[i][r]);
          m2[i][r] = fminf(m2[i][r], hi);
          bool lt = sv < m1[i][r];
          m1[i][r] = lt ? sv : m1[i][r];
          mcx[i][r] = lt ? col : mcx[i][r];
        }
    }
  }
#undef STAGE

  // ---- merge across the 16 code-lanes (same queries, disjoint codes) ----
#pragma unroll
  for (int m = 1; m < 16; m <<= 1) {
#pragma unroll
    for (int i = 0; i < 2; ++i)
#pragma unroll
      for (int r = 0; r < 4; ++r) {
        float o1 = __shfl_xor(m1[i][r], m);
        float o2 = __shfl_xor(m2[i][r], m);
        int   oc = __shfl_xor(mcx[i][r], m);
        float hi = fmaxf(o1, m1[i][r]);
        m2[i][r] = fminf(fminf(m2[i][r], o2), hi);
        bool lt = o1 < m1[i][r];
        m1[i][r] = lt ? o1 : m1[i][r];
        mcx[i][r] = lt ? oc : mcx[i][r];
      }
  }
  if (c == 0) {
#pragma unroll
    for (int i = 0; i < 2; ++i)
#pragma unroll
      for (int r = 0; r < 4; ++r) {
        int query = qbase + i * 16 + q * 4 + r;
        idx[query] = mcx[i][r];
        if (m2[i][r] - m1[i][r] < TAU_S) { int p = atomicAdd(counter, 1); list[p] = query; }
      }
  }
}

// ---------------- trans: cb [1024][512] -> cbT [512][1024] (fp32) ----------------
__global__ __launch_bounds__(256) void vq_trans(const float4* __restrict__ cb4,
                                                float4* __restrict__ cbT4) {
  __shared__ float t[64][65];
  const int bc = blockIdx.x >> 3, bk = blockIdx.x & 7;
  const int c0 = bc * 64, k0 = bk * 64;
  const int r = threadIdx.x >> 4, q4 = threadIdx.x & 15;
#pragma unroll
  for (int p = 0; p < 4; ++p) {
    int row = p * 16 + r;
    float4 v = cb4[(size_t)(c0 + row) * 128 + (k0 >> 2) + q4];
    t[row][q4 * 4 + 0] = v.x; t[row][q4 * 4 + 1] = v.y;
    t[row][q4 * 4 + 2] = v.z; t[row][q4 * 4 + 3] = v.w;
  }
  __syncthreads();
#pragma unroll
  for (int p = 0; p < 4; ++p) {
    int kk = p * 16 + r;
    float4 v = make_float4(t[q4 * 4 + 0][kk], t[q4 * 4 + 1][kk],
                           t[q4 * 4 + 2][kk], t[q4 * 4 + 3][kk]);
    cbT4[(size_t)(k0 + kk) * 256 + (c0 >> 2) + q4] = v;
  }
}

// ---------------- refine: exact fp64 re-scan, 8 queries per cbT sweep ----------------
__global__ __launch_bounds__(256) void vq_refine(const float* __restrict__ x,
                                                 const float4* __restrict__ cbT4,
                                                 const double* __restrict__ c2d,
                                                 const int* __restrict__ list,
                                                 const int* __restrict__ counter,
                                                 int* __restrict__ idx) {
  __shared__ __align__(16) float xs[8][512];    // 16 KB
  __shared__ int qlist[8];
  __shared__ double rv[8][4];
  __shared__ int rc[8][4];
  const int cnt = counter[0];
  const int tid = threadIdx.x, lane = tid & 63, wv = tid >> 6;
  for (int base = blockIdx.x * 8; base < cnt; base += gridDim.x * 8) {
    const int nq = min(8, cnt - base);
    __syncthreads();                            // protect xs/rv reuse
    if (tid < 8) qlist[tid] = list[base + ((tid < nq) ? tid : 0)];
    __syncthreads();
#pragma unroll
    for (int k = 0; k < 4; ++k) {
      int e = tid + 256 * k;                    // float4 slot 0..1023
      int qi = e >> 7, d4 = e & 127;
      ((float4*)xs)[e] = ((const float4*)(x + (size_t)qlist[qi] * KDIM))[d4];
    }
    __syncthreads();
    double a0[8], a1[8], a2[8], a3[8];
#pragma unroll
    for (int qi = 0; qi < 8; ++qi) { a0[qi] = 0; a1[qi] = 0; a2[qi] = 0; a3[qi] = 0; }
#pragma unroll 2
    for (int k4 = 0; k4 < 128; ++k4) {
      float4 c0 = cbT4[(k4 * 4 + 0) * 256 + tid];
      float4 c1 = cbT4[(k4 * 4 + 1) * 256 + tid];
      float4 c2v = cbT4[(k4 * 4 + 2) * 256 + tid];
      float4 c3 = cbT4[(k4 * 4 + 3) * 256 + tid];
#pragma unroll
      for (int qi = 0; qi < 8; ++qi) {
        float4 xv = *(const float4*)&xs[qi][k4 * 4];
        a0[qi] = fma((double)xv.x, (double)c0.x, a0[qi]);
        a1[qi] = fma((double)xv.x, (double)c0.y, a1[qi]);
        a2[qi] = fma((double)xv.x, (double)c0.z, a2[qi]);
        a3[qi] = fma((double)xv.x, (double)c0.w, a3[qi]);
        a0[qi] = fma((double)xv.y, (double)c1.x, a0[qi]);
        a1[qi] = fma((double)xv.y, (double)c1.y, a1[qi]);
        a2[qi] = fma((double)xv.y, (double)c1.z, a2[qi]);
        a3[qi] = fma((double)xv.y, (double)c1.w, a3[qi]);
        a0[qi] = fma((double)xv.z, (double)c2v.x, a0[qi]);
        a1[qi] = fma((double)xv.z, (double)c2v.y, a1[qi]);
        a2[qi] = fma((double)xv.z, (double)c2v.z, a2[qi]);
        a3[qi] = fma((double)xv.z, (double)c2v.w, a3[qi]);
        a0[qi] = fma((double)xv.w, (double)c3.x, a0[qi]);
        a1[qi] = fma((double)xv.w, (double)c3.y, a1[qi]);
        a2[qi] = fma((double)xv.w, (double)c3.z, a2[qi]);
        a3[qi] = fma((double)xv.w, (double)c3.w, a3[qi]);
      }
    }
    const double c2l0 = c2d[tid * 4], c2l1 = c2d[tid * 4 + 1];
    const double c2l2 = c2d[tid * 4 + 2], c2l3 = c2d[tid * 4 + 3];
#pragma unroll
    for (int qi = 0; qi < 8; ++qi) {
      double best = c2l0 - a0[qi];
      int bc = tid * 4;
      double s1 = c2l1 - a1[qi];
      if (s1 < best) { best = s1; bc = tid * 4 + 1; }
      double s2 = c2l2 - a2[qi];
      if (s2 < best) { best = s2; bc = tid * 4 + 2; }
      double s3 = c2l3 - a3[qi];
      if (s3 < best) { best = s3; bc = tid * 4 + 3; }
#pragma unroll
      for (int m = 1; m < 64; m <<= 1) {
        double o = __shfl_xor(best, m);
        int oc = __shfl_xor(bc, m);
        if (o < best) { best = o; bc = oc; }
      }
      if (lane == 0) { rv[qi][wv] = best; rc[qi][wv] = bc; }
    }
    __syncthreads();
    if (tid < nq) {
      double b = rv[tid][0];
      int bci = rc[tid][0];
#pragma unroll
      for (int w = 1; w < 4; ++w)
        if (rv[tid][w] < b) { b = rv[tid][w]; bci = rc[tid][w]; }
      idx[qlist[tid]] = bci;
    }
  }
}

// ---------------- gather: out[q] = codebook[idx[q]] ----------------
__global__ __launch_bounds__(256) void vq_gather(const float* __restrict__ cb,
                                                 const int* __restrict__ idx,
                                                 float* __restrict__ out) {
  size_t i = (size_t)blockIdx.x * 256 + threadIdx.x;
  int qg = (int)(i >> 7), d = (int)(i & 127);
  ((float4*)out)[i] = ((const float4*)cb)[(size_t)idx[qg] * 128 + d];
}

extern "C" void kernel_launch(void* const* d_in, const int* in_sizes, int n_in,
                              void* d_out, int out_size, void* d_ws, size_t ws_size,
                              hipStream_t stream) {
  const float* x = (const float*)d_in[0];
  const float* cb = (const float*)d_in[1];
  float* out = (float*)d_out;
  char* ws = (char*)d_ws;
  if (ws_size < WS_NEED) {
    fprintf(stderr, "vq: ws_size %zu too small (need %llu)\n", ws_size,
            (unsigned long long)WS_NEED);
    return;
  }
  unsigned short* cbh = (unsigned short*)(ws + WS_CBH);
  float* c2h = (float*)(ws + WS_C2H);
  double* c2d = (double*)(ws + WS_C2D);
  float* cbT = (float*)(ws + WS_CBT);
  int* idx = (int*)(ws + WS_IDX);
  int* list = (int*)(ws + WS_LIST);
  int* counter = (int*)(ws + WS_CTR);

  hipMemsetAsync(counter, 0, 4, stream);
  vq_prep<<<256, 256, 0, stream>>>(cb, cbh, c2h, c2d);
  vq_trans<<<128, 256, 0, stream>>>((const float4*)cb, (float4*)cbT);
  vq_main<<<256, 512, 0, stream>>>(x, cbh, c2h, idx, list, counter);
  vq_refine<<<2048, 256, 0, stream>>>(x, (const float4*)cbT, c2d, list, counter, idx);
  vq_gather<<<32768, 256, 0, stream>>>(cb, idx, out);
}

// Round 3
// 401.646 us; speedup vs baseline: 1.0423x; 1.0423x over previous
//
#include <hip/hip_runtime.h>
#include <cstdio>

// VQ nearest-codebook, round 7.
// vq_main: 256 thr / 4 waves, each wave owns 64 query rows fully in registers
// (a[4][16] half8 = 256 VGPR); codebook streamed through LDS in 16
// double-buffered 64-code chunks. Halves LDS read traffic vs R6 (4 MB/CU):
// the R6 limiter was the LDS read pipe (8 waves x full-B re-read), not HBM.
// vq_refine reverted to 1-query-per-block grid-stride (R6's 8-query batching
// serialized ~100 flagged queries onto ~13 blocks -> 119 us at 2.6% occ).
// fp16 stage-1 + TAU 0.05 + exact fp64 refine of flagged + gather.

typedef float f32x4 __attribute__((ext_vector_type(4)));
typedef _Float16 half8 __attribute__((ext_vector_type(8)));

#define KDIM 512
#define NCODES 1024
#define NQ 65536
#define TAU_S 0.05f   // fp16 dot err sigma ~0.009; 0.05 ~ 5.5 sigma (passed R3-R6, absmax 0)

// ---- workspace layout (bytes) ----
#define WS_CBH   0ull                         // fp16 cb [1024][512]   1048576
#define WS_C2H   1048576ull                   // float 0.5||c||^2 [1024]  4096
#define WS_C2D   1052672ull                   // double 0.5||c||^2 [1024] 8192
#define WS_CBT   1060864ull                   // fp32 cbT [512][1024]  2097152
#define WS_IDX   3158016ull                   // int [65536]            262144
#define WS_LIST  3420160ull                   // int [65536]            262144
#define WS_CTR   3682304ull                   // int
#define WS_NEED  (WS_CTR + 4ull)

__device__ __forceinline__ unsigned short f2h(float f) {
  _Float16 h = (_Float16)f;                   // RNE
  return __builtin_bit_cast(unsigned short, h);
}

__device__ __forceinline__ void async16(const void* g, void* l) {
  __builtin_amdgcn_global_load_lds(
      (const __attribute__((address_space(1))) void*)g,
      (__attribute__((address_space(3))) void*)l, 16, 0, 0);
}

// ---------------- prep: codebook -> fp16 row-major + 0.5||c||^2 ----------------
__global__ __launch_bounds__(256) void vq_prep(const float* __restrict__ cb,
                                               unsigned short* __restrict__ cbh,
                                               float* __restrict__ c2h,
                                               double* __restrict__ c2d) {
  int lane = threadIdx.x & 63;
  int row = blockIdx.x * 4 + (threadIdx.x >> 6);
  const float4* src = (const float4*)(cb + (size_t)row * KDIM);
  float4 u = src[lane * 2], v = src[lane * 2 + 1];
  double p = (double)u.x * u.x + (double)u.y * u.y + (double)u.z * u.z + (double)u.w * u.w +
             (double)v.x * v.x + (double)v.y * v.y + (double)v.z * v.z + (double)v.w * v.w;
#pragma unroll
  for (int m = 1; m < 64; m <<= 1) p += __shfl_xor(p, m);
  if (lane == 0) { c2h[row] = (float)(0.5 * p); c2d[row] = 0.5 * p; }
  unsigned r0 = f2h(u.x) | ((unsigned)f2h(u.y) << 16);
  unsigned r1 = f2h(u.z) | ((unsigned)f2h(u.w) << 16);
  unsigned r2 = f2h(v.x) | ((unsigned)f2h(v.y) << 16);
  unsigned r3 = f2h(v.z) | ((unsigned)f2h(v.w) << 16);
  *(int4*)(cbh + (size_t)row * KDIM + lane * 8) = make_int4((int)r0, (int)r1, (int)r2, (int)r3);
}

// ---------------- main: A-in-registers (64 rows/wave), B streamed via LDS ----------------
// grid 256 x 256 thr (4 waves). Wave wv owns 64 query rows (full K=512 in regs).
// LDS: Bs[2][64 codes][512 halfs] = 128 KB dbuf + c2s[1024] floats = 4 KB.
// Chunk loop (16 x 64 codes): single __syncthreads per chunk; STAGE(ch+1)
// issued right after the barrier into the non-active buffer, drains at the
// NEXT barrier's implicit vmcnt(0) -> ~3k cyc latency slack.
// LDS swizzle: 16B-granule g within a 1024B row stored at g^(row&7); staging
// writes row r linearly per wave (dest lane-linear) with source granule
// lane^(r&7); reads use granule ((kf*4+q)^(c&7)) at row cf*16+c.
__global__ __launch_bounds__(256, 1) void vq_main(const float* __restrict__ x,
                                                  const unsigned short* __restrict__ cbh,
                                                  const float* __restrict__ c2h,
                                                  int* __restrict__ idx,
                                                  int* __restrict__ list,
                                                  int* __restrict__ counter) {
  __shared__ __align__(16) char pool[135168];
  float* c2s = (float*)(pool + 131072);

  const int tid = threadIdx.x;
  const int lane = tid & 63, wv = tid >> 6;
  const int c = lane & 15, q = lane >> 4;
  const int qbase = blockIdx.x * 256 + wv * 64;

#define STAGE(cc) do {                                                        \
    const unsigned short* _s = cbh + (size_t)(cc) * 32768;                    \
    char* _d = pool + (((cc) & 1) * 65536);                                   \
    _Pragma("unroll")                                                         \
    for (int s = 0; s < 16; ++s) {                                            \
      int r = wv * 16 + s;                                                    \
      async16(_s + (size_t)r * 512 + ((lane ^ (r & 7)) * 8),                  \
              _d + r * 1024 + lane * 16);                                     \
    } } while (0)

  // ---- issue c2s + chunk-0 staging first (in flight during A-load) ----
  async16(c2h + wv * 256 + lane * 4, pool + 131072 + wv * 1024 + lane * 16);
  STAGE(0);

  // ---- A-load: 64 rows x 512 dims fp32 -> fp16 fragments in registers ----
  // frag (rf,kf): lane holds x[qbase + rf*16 + c][kf*32 + q*8 .. +7]
  half8 a[4][16];
#pragma unroll
  for (int rf = 0; rf < 4; ++rf) {
    const float* xr = x + (size_t)(qbase + rf * 16 + c) * KDIM + q * 8;
    float4 t[32];
#pragma unroll
    for (int kf = 0; kf < 16; ++kf) {
      t[kf * 2]     = *(const float4*)(xr + kf * 32);
      t[kf * 2 + 1] = *(const float4*)(xr + kf * 32 + 4);
    }
#pragma unroll
    for (int kf = 0; kf < 16; ++kf) {
      float4 lo = t[kf * 2], hi = t[kf * 2 + 1];
      half8 h;
      h[0] = (_Float16)lo.x; h[1] = (_Float16)lo.y;
      h[2] = (_Float16)lo.z; h[3] = (_Float16)lo.w;
      h[4] = (_Float16)hi.x; h[5] = (_Float16)hi.y;
      h[6] = (_Float16)hi.z; h[7] = (_Float16)hi.w;
      a[rf][kf] = h;
    }
    __builtin_amdgcn_sched_barrier(0);
  }

  // ---- running (min1, min2, argmin) per (rf, r) ----
  float m1[4][4], m2[4][4];
  int mcx[4][4];
#pragma unroll
  for (int i = 0; i < 4; ++i)
#pragma unroll
    for (int r = 0; r < 4; ++r) { m1[i][r] = 1e30f; m2[i][r] = 1e30f; mcx[i][r] = 0; }

  const int m3 = c & 7;

#pragma unroll 1
  for (int ch = 0; ch < 16; ++ch) {
    __syncthreads();                 // implicit vmcnt(0): stage(ch) landed for all
    if (ch + 1 < 16) STAGE(ch + 1); // into buf[(ch+1)&1] (not read this iter)

    const unsigned short* B = (const unsigned short*)(pool + ((ch & 1) * 65536));
    f32x4 acc[4][4];
#pragma unroll
    for (int i = 0; i < 4; ++i)
#pragma unroll
      for (int j = 0; j < 4; ++j) acc[i][j] = (f32x4){0.f, 0.f, 0.f, 0.f};

#pragma unroll
    for (int kf = 0; kf < 16; ++kf) {
      half8 b[4];
      const int gg = (kf * 4 + q) ^ m3;
#pragma unroll
      for (int cf = 0; cf < 4; ++cf)
        b[cf] = *(const half8*)&B[(cf * 16 + c) * 512 + gg * 8];
#pragma unroll
      for (int i = 0; i < 4; ++i)
#pragma unroll
        for (int cf = 0; cf < 4; ++cf)
          acc[i][cf] = __builtin_amdgcn_mfma_f32_16x16x32_f16(a[i][kf], b[cf], acc[i][cf], 0, 0, 0);
    }
    // fold chunk scores into running min-state
#pragma unroll
    for (int cf = 0; cf < 4; ++cf) {
      const int col = ch * 64 + cf * 16 + c;
      const float c2v = c2s[col];
#pragma unroll
      for (int i = 0; i < 4; ++i)
#pragma unroll
        for (int r = 0; r < 4; ++r) {
          float sv = c2v - acc[i][cf][r];
          float hi = fmaxf(sv, m1[i][r]);
          m2[i][r] = fminf(m2[i][r], hi);
          bool lt = sv < m1[i][r];
          m1[i][r] = lt ? sv : m1[i][r];
          mcx[i][r] = lt ? col : mcx[i][r];
        }
    }
  }
#undef STAGE

  // ---- merge across the 16 code-lanes (same queries, disjoint codes) ----
#pragma unroll
  for (int m = 1; m < 16; m <<= 1) {
#pragma unroll
    for (int i = 0; i < 4; ++i)
#pragma unroll
      for (int r = 0; r < 4; ++r) {
        float o1 = __shfl_xor(m1[i][r], m);
        float o2 = __shfl_xor(m2[i][r], m);
        int   oc = __shfl_xor(mcx[i][r], m);
        float hi = fmaxf(o1, m1[i][r]);
        m2[i][r] = fminf(fminf(m2[i][r], o2), hi);
        bool lt = o1 < m1[i][r];
        m1[i][r] = lt ? o1 : m1[i][r];
        mcx[i][r] = lt ? oc : mcx[i][r];
      }
  }
  if (c == 0) {
#pragma unroll
    for (int i = 0; i < 4; ++i)
#pragma unroll
      for (int r = 0; r < 4; ++r) {
        int query = qbase + i * 16 + q * 4 + r;
        idx[query] = mcx[i][r];
        if (m2[i][r] - m1[i][r] < TAU_S) { int p = atomicAdd(counter, 1); list[p] = query; }
      }
  }
}

// ---------------- trans: cb [1024][512] -> cbT [512][1024] (fp32) ----------------
__global__ __launch_bounds__(256) void vq_trans(const float4* __restrict__ cb4,
                                                float4* __restrict__ cbT4) {
  __shared__ float t[64][65];
  const int bc = blockIdx.x >> 3, bk = blockIdx.x & 7;
  const int c0 = bc * 64, k0 = bk * 64;
  const int r = threadIdx.x >> 4, q4 = threadIdx.x & 15;
#pragma unroll
  for (int p = 0; p < 4; ++p) {
    int row = p * 16 + r;
    float4 v = cb4[(size_t)(c0 + row) * 128 + (k0 >> 2) + q4];
    t[row][q4 * 4 + 0] = v.x; t[row][q4 * 4 + 1] = v.y;
    t[row][q4 * 4 + 2] = v.z; t[row][q4 * 4 + 3] = v.w;
  }
  __syncthreads();
#pragma unroll
  for (int p = 0; p < 4; ++p) {
    int kk = p * 16 + r;
    float4 v = make_float4(t[q4 * 4 + 0][kk], t[q4 * 4 + 1][kk],
                           t[q4 * 4 + 2][kk], t[q4 * 4 + 3][kk]);
    cbT4[(size_t)(k0 + kk) * 256 + (c0 >> 2) + q4] = v;
  }
}

// ---------------- refine: exact fp64 re-scan, lane-per-4-codes, 1 query/block ----------------
__global__ __launch_bounds__(256) void vq_refine(const float* __restrict__ x,
                                                 const float4* __restrict__ cbT4,
                                                 const double* __restrict__ c2d,
                                                 const int* __restrict__ list,
                                                 const int* __restrict__ counter,
                                                 int* __restrict__ idx) {
  __shared__ float xs[512];
  __shared__ double rv[4];
  __shared__ int rc[4];
  const int cnt = counter[0];
  const int tid = threadIdx.x, lane = tid & 63, wv = tid >> 6;
  for (int qi = blockIdx.x; qi < cnt; qi += gridDim.x) {
    const int query = list[qi];
    __syncthreads();
    xs[tid] = x[(size_t)query * KDIM + tid];
    xs[tid + 256] = x[(size_t)query * KDIM + tid + 256];
    __syncthreads();
    double a0 = 0, a1 = 0, a2 = 0, a3 = 0;
    const float4* xs4 = (const float4*)xs;
#pragma unroll 4
    for (int k4 = 0; k4 < 128; ++k4) {
      float4 xv = xs4[k4];
      float4 c0 = cbT4[(k4 * 4 + 0) * 256 + tid];
      float4 c1 = cbT4[(k4 * 4 + 1) * 256 + tid];
      float4 c2v = cbT4[(k4 * 4 + 2) * 256 + tid];
      float4 c3 = cbT4[(k4 * 4 + 3) * 256 + tid];
      a0 = fma((double)xv.x, (double)c0.x, a0);
      a1 = fma((double)xv.x, (double)c0.y, a1);
      a2 = fma((double)xv.x, (double)c0.z, a2);
      a3 = fma((double)xv.x, (double)c0.w, a3);
      a0 = fma((double)xv.y, (double)c1.x, a0);
      a1 = fma((double)xv.y, (double)c1.y, a1);
      a2 = fma((double)xv.y, (double)c1.z, a2);
      a3 = fma((double)xv.y, (double)c1.w, a3);
      a0 = fma((double)xv.z, (double)c2v.x, a0);
      a1 = fma((double)xv.z, (double)c2v.y, a1);
      a2 = fma((double)xv.z, (double)c2v.z, a2);
      a3 = fma((double)xv.z, (double)c2v.w, a3);
      a0 = fma((double)xv.w, (double)c3.x, a0);
      a1 = fma((double)xv.w, (double)c3.y, a1);
      a2 = fma((double)xv.w, (double)c3.z, a2);
      a3 = fma((double)xv.w, (double)c3.w, a3);
    }
    double best = c2d[tid * 4] - a0;
    int bc = tid * 4;
    double s1 = c2d[tid * 4 + 1] - a1;
    if (s1 < best) { best = s1; bc = tid * 4 + 1; }
    double s2 = c2d[tid * 4 + 2] - a2;
    if (s2 < best) { best = s2; bc = tid * 4 + 2; }
    double s3 = c2d[tid * 4 + 3] - a3;
    if (s3 < best) { best = s3; bc = tid * 4 + 3; }
#pragma unroll
    for (int m = 1; m < 64; m <<= 1) {
      double o = __shfl_xor(best, m);
      int oc = __shfl_xor(bc, m);
      if (o < best) { best = o; bc = oc; }
    }
    if (lane == 0) { rv[wv] = best; rc[wv] = bc; }
    __syncthreads();
    if (tid == 0) {
      double b = rv[0]; int bci = rc[0];
#pragma unroll
      for (int w = 1; w < 4; ++w)
        if (rv[w] < b) { b = rv[w]; bci = rc[w]; }
      idx[query] = bci;
    }
    __syncthreads();
  }
}

// ---------------- gather: out[q] = codebook[idx[q]] ----------------
__global__ __launch_bounds__(256) void vq_gather(const float* __restrict__ cb,
                                                 const int* __restrict__ idx,
                                                 float* __restrict__ out) {
  size_t i = (size_t)blockIdx.x * 256 + threadIdx.x;
  int qg = (int)(i >> 7), d = (int)(i & 127);
  ((float4*)out)[i] = ((const float4*)cb)[(size_t)idx[qg] * 128 + d];
}

extern "C" void kernel_launch(void* const* d_in, const int* in_sizes, int n_in,
                              void* d_out, int out_size, void* d_ws, size_t ws_size,
                              hipStream_t stream) {
  const float* x = (const float*)d_in[0];
  const float* cb = (const float*)d_in[1];
  float* out = (float*)d_out;
  char* ws = (char*)d_ws;
  if (ws_size < WS_NEED) {
    fprintf(stderr, "vq: ws_size %zu too small (need %llu)\n", ws_size,
            (unsigned long long)WS_NEED);
    return;
  }
  unsigned short* cbh = (unsigned short*)(ws + WS_CBH);
  float* c2h = (float*)(ws + WS_C2H);
  double* c2d = (double*)(ws + WS_C2D);
  float* cbT = (float*)(ws + WS_CBT);
  int* idx = (int*)(ws + WS_IDX);
  int* list = (int*)(ws + WS_LIST);
  int* counter = (int*)(ws + WS_CTR);

  hipMemsetAsync(counter, 0, 4, stream);
  vq_prep<<<256, 256, 0, stream>>>(cb, cbh, c2h, c2d);
  vq_trans<<<128, 256, 0, stream>>>((const float4*)cb, (float4*)cbT);
  vq_main<<<256, 256, 0, stream>>>(x, cbh, c2h, idx, list, counter);
  vq_refine<<<2048, 256, 0, stream>>>(x, (const float4*)cbT, c2d, list, counter, idx);
  vq_gather<<<32768, 256, 0, stream>>>(cb, idx, out);
}

// Round 5
// 353.665 us; speedup vs baseline: 1.1837x; 1.1357x over previous
//
#include <hip/hip_runtime.h>
#include <cstdio>

// VQ nearest-codebook, round 8b (compile fix: nontemporal store via ext-vector).
// vq_main: R6 geometry (8 waves x 32 rows-in-reg, 2 waves/SIMD) + counted
// vmcnt (T4) via 3-buffer chunk rotation: per 32-code chunk exactly one
// s_waitcnt vmcnt(4) (never 0 mid-loop) + one raw s_barrier + sched_barrier
// fence; chunk ch+2 staged into the buffer last read at ch-1 (WAR-safe
// behind the single barrier). Swizzle S(r)=((r&1)<<2)|((r>>1)&3)
// (bijective on c&7 AND spreads q over bit2 -> kills the measured 4-way
// q-quad conflict, 8.4M -> ~0). gather: 2048-block grid-stride +
// nontemporal stores; prep+trans fused into one launch.
// fp16 stage-1 + TAU 0.05 + exact fp64 refine of flagged + gather.

typedef float f32x4 __attribute__((ext_vector_type(4)));
typedef _Float16 half8 __attribute__((ext_vector_type(8)));

#define KDIM 512
#define NCODES 1024
#define NQ 65536
#define TAU_S 0.05f   // fp16 dot err sigma ~0.009; 0.05 ~ 5.5 sigma (passed R3-R7, absmax 0)

// ---- workspace layout (bytes) ----
#define WS_CBH   0ull                         // fp16 cb [1024][512]   1048576
#define WS_C2H   1048576ull                   // float 0.5||c||^2 [1024]  4096
#define WS_C2D   1052672ull                   // double 0.5||c||^2 [1024] 8192
#define WS_CBT   1060864ull                   // fp32 cbT [512][1024]  2097152
#define WS_IDX   3158016ull                   // int [65536]            262144
#define WS_LIST  3420160ull                   // int [65536]            262144
#define WS_CTR   3682304ull                   // int
#define WS_NEED  (WS_CTR + 4ull)

__device__ __forceinline__ unsigned short f2h(float f) {
  _Float16 h = (_Float16)f;                   // RNE
  return __builtin_bit_cast(unsigned short, h);
}

__device__ __forceinline__ void async16(const void* g, void* l) {
  __builtin_amdgcn_global_load_lds(
      (const __attribute__((address_space(1))) void*)g,
      (__attribute__((address_space(3))) void*)l, 16, 0, 0);
}

#define SB0 __builtin_amdgcn_sched_barrier(0)

// ---------------- prep (fused): blocks 0..255 -> cbh/c2h/c2d; 256..383 -> cbT ----------------
__global__ __launch_bounds__(256) void vq_prep(const float* __restrict__ cb,
                                               unsigned short* __restrict__ cbh,
                                               float* __restrict__ c2h,
                                               double* __restrict__ c2d,
                                               float4* __restrict__ cbT4) {
  __shared__ float t[64][65];
  if (blockIdx.x < 256) {
    int lane = threadIdx.x & 63;
    int row = blockIdx.x * 4 + (threadIdx.x >> 6);
    const float4* src = (const float4*)(cb + (size_t)row * KDIM);
    float4 u = src[lane * 2], v = src[lane * 2 + 1];
    double p = (double)u.x * u.x + (double)u.y * u.y + (double)u.z * u.z + (double)u.w * u.w +
               (double)v.x * v.x + (double)v.y * v.y + (double)v.z * v.z + (double)v.w * v.w;
#pragma unroll
    for (int m = 1; m < 64; m <<= 1) p += __shfl_xor(p, m);
    if (lane == 0) { c2h[row] = (float)(0.5 * p); c2d[row] = 0.5 * p; }
    unsigned r0 = f2h(u.x) | ((unsigned)f2h(u.y) << 16);
    unsigned r1 = f2h(u.z) | ((unsigned)f2h(u.w) << 16);
    unsigned r2 = f2h(v.x) | ((unsigned)f2h(v.y) << 16);
    unsigned r3 = f2h(v.z) | ((unsigned)f2h(v.w) << 16);
    *(int4*)(cbh + (size_t)row * KDIM + lane * 8) = make_int4((int)r0, (int)r1, (int)r2, (int)r3);
    return;
  }
  // trans role: cb [1024][512] -> cbT [512][1024]
  const int bb = blockIdx.x - 256;
  const float4* cb4 = (const float4*)cb;
  const int bc = bb >> 3, bk = bb & 7;
  const int c0 = bc * 64, k0 = bk * 64;
  const int r = threadIdx.x >> 4, q4 = threadIdx.x & 15;
#pragma unroll
  for (int p = 0; p < 4; ++p) {
    int row = p * 16 + r;
    float4 v = cb4[(size_t)(c0 + row) * 128 + (k0 >> 2) + q4];
    t[row][q4 * 4 + 0] = v.x; t[row][q4 * 4 + 1] = v.y;
    t[row][q4 * 4 + 2] = v.z; t[row][q4 * 4 + 3] = v.w;
  }
  __syncthreads();
#pragma unroll
  for (int p = 0; p < 4; ++p) {
    int kk = p * 16 + r;
    float4 v = make_float4(t[q4 * 4 + 0][kk], t[q4 * 4 + 1][kk],
                           t[q4 * 4 + 2][kk], t[q4 * 4 + 3][kk]);
    cbT4[(size_t)(k0 + kk) * 256 + (c0 >> 2) + q4] = v;
  }
}

// ---------------- main: A-in-registers (32 rows/wave), B streamed via LDS ----------------
// grid 256 x 512 thr (8 waves, 2/SIMD). Wave owns 32 query rows (full K=512
// in regs, a[2][16] = 128 VGPR). B: 32 chunks of 32 codes; LDS 3 x 32KB
// rotation + c2s 4KB. Per chunk: vmcnt(4) -> s_barrier -> sched_barrier ->
// stage(ch+2) -> 16kf x {2 ds_read_b128 + 4 MFMA} -> fold.
// Swizzle: granule n of row r stored at n ^ S(r), S = ((r&1)<<2)|((r>>1)&3).
__global__ __launch_bounds__(512, 2) void vq_main(const float* __restrict__ x,
                                                  const unsigned short* __restrict__ cbh,
                                                  const float* __restrict__ c2h,
                                                  int* __restrict__ idx,
                                                  int* __restrict__ list,
                                                  int* __restrict__ counter) {
  __shared__ __align__(16) char pool[102400];  // 3*32768 B + 4096 c2s
  float* c2s = (float*)(pool + 98304);

  const int tid = threadIdx.x;
  const int lane = tid & 63, wv = tid >> 6;
  const int c = lane & 15, q = lane >> 4;
  const int qbase = blockIdx.x * 256 + wv * 32;
  const int Sc = ((c & 1) << 2) | ((c >> 1) & 3);

#define STAGE(ch2, sb) do {                                                   \
    const unsigned short* _s = cbh + (size_t)(ch2) * 16384;                   \
    char* _d = pool + (sb) * 32768;                                           \
    _Pragma("unroll")                                                         \
    for (int s = 0; s < 4; ++s) {                                             \
      int r = wv * 4 + s;                                                     \
      int Sr = ((r & 1) << 2) | ((r >> 1) & 3);                               \
      async16(_s + r * 512 + ((lane ^ Sr) * 8), _d + r * 1024 + lane * 16);   \
    } } while (0)

  // ---- prologue: c2s + chunks 0,1 in flight ----
  if (wv < 4) async16(c2h + wv * 256 + lane * 4, pool + 98304 + wv * 1024 + lane * 16);
  STAGE(0, 0);
  STAGE(1, 1);
  SB0;

  // ---- A-load: 32 rows x 512 dims fp32 -> fp16 fragments in registers ----
  // frag (rf,kf): lane holds x[qbase + rf*16 + c][kf*32 + q*8 .. +7]
  half8 a[2][16];
#pragma unroll
  for (int rf = 0; rf < 2; ++rf) {
    const float* xr = x + (size_t)(qbase + rf * 16 + c) * KDIM + q * 8;
#pragma unroll
    for (int blk = 0; blk < 4; ++blk) {
      float4 t[8];
#pragma unroll
      for (int s = 0; s < 4; ++s) {
        int kf = blk * 4 + s;
        t[s * 2]     = *(const float4*)(xr + kf * 32);
        t[s * 2 + 1] = *(const float4*)(xr + kf * 32 + 4);
      }
#pragma unroll
      for (int s = 0; s < 4; ++s) {
        float4 lo = t[s * 2], hi = t[s * 2 + 1];
        half8 h;
        h[0] = (_Float16)lo.x; h[1] = (_Float16)lo.y;
        h[2] = (_Float16)lo.z; h[3] = (_Float16)lo.w;
        h[4] = (_Float16)hi.x; h[5] = (_Float16)hi.y;
        h[6] = (_Float16)hi.z; h[7] = (_Float16)hi.w;
        a[rf][blk * 4 + s] = h;
      }
    }
  }
  SB0;

  // ---- running (min1, min2, argmin) per (rf, r) ----
  float m1[2][4], m2[2][4];
  int mcx[2][4];
#pragma unroll
  for (int i = 0; i < 2; ++i)
#pragma unroll
    for (int r = 0; r < 4; ++r) { m1[i][r] = 1e30f; m2[i][r] = 1e30f; mcx[i][r] = 0; }

#define BODY(cur, chv) do {                                                   \
    const unsigned short* B = (const unsigned short*)(pool + (cur) * 32768);  \
    f32x4 acc[2][2];                                                          \
    acc[0][0] = (f32x4){0.f,0.f,0.f,0.f}; acc[0][1] = (f32x4){0.f,0.f,0.f,0.f};\
    acc[1][0] = (f32x4){0.f,0.f,0.f,0.f}; acc[1][1] = (f32x4){0.f,0.f,0.f,0.f};\
    _Pragma("unroll")                                                         \
    for (int kf = 0; kf < 16; ++kf) {                                         \
      const int gg = (kf * 4 + q) ^ Sc;                                       \
      half8 b0 = *(const half8*)&B[(size_t)c * 512 + gg * 8];                 \
      half8 b1 = *(const half8*)&B[(size_t)(16 + c) * 512 + gg * 8];          \
      acc[0][0] = __builtin_amdgcn_mfma_f32_16x16x32_f16(a[0][kf], b0, acc[0][0], 0, 0, 0); \
      acc[1][0] = __builtin_amdgcn_mfma_f32_16x16x32_f16(a[1][kf], b0, acc[1][0], 0, 0, 0); \
      acc[0][1] = __builtin_amdgcn_mfma_f32_16x16x32_f16(a[0][kf], b1, acc[0][1], 0, 0, 0); \
      acc[1][1] = __builtin_amdgcn_mfma_f32_16x16x32_f16(a[1][kf], b1, acc[1][1], 0, 0, 0); \
    }                                                                         \
    _Pragma("unroll")                                                         \
    for (int cf = 0; cf < 2; ++cf) {                                          \
      const int col = (chv) * 32 + cf * 16 + c;                               \
      const float c2v = c2s[col];                                             \
      _Pragma("unroll")                                                       \
      for (int i = 0; i < 2; ++i)                                             \
        _Pragma("unroll")                                                     \
        for (int r = 0; r < 4; ++r) {                                         \
          float sv = c2v - acc[i][cf][r];                                     \
          float hi = fmaxf(sv, m1[i][r]);                                     \
          m2[i][r] = fminf(m2[i][r], hi);                                     \
          bool lt = sv < m1[i][r];                                            \
          m1[i][r] = lt ? sv : m1[i][r];                                      \
          mcx[i][r] = lt ? col : mcx[i][r];                                   \
        }                                                                     \
    } } while (0)

  int cur = 0;
#pragma unroll 1
  for (int ch = 0; ch < 31; ++ch) {
    asm volatile("s_waitcnt vmcnt(4)" ::: "memory");   // chunk ch landed (mine); ch+1 in flight
    SB0;
    __builtin_amdgcn_s_barrier();                      // all waves' chunk-ch loads landed
    SB0;                                               // nothing crosses above the barrier
    if (ch < 30) {
      int sb = cur + 2; if (sb >= 3) sb -= 3;          // buffer last read at ch-1: free
      STAGE(ch + 2, sb);
    }
    BODY(cur, ch);
    cur = cur + 1; if (cur == 3) cur = 0;
  }
  asm volatile("s_waitcnt vmcnt(0)" ::: "memory");     // last chunk: nothing behind it
  SB0;
  __builtin_amdgcn_s_barrier();
  SB0;
  BODY(cur, 31);
#undef STAGE
#undef BODY

  // ---- merge across the 16 code-lanes (same queries, disjoint codes) ----
#pragma unroll
  for (int m = 1; m < 16; m <<= 1) {
#pragma unroll
    for (int i = 0; i < 2; ++i)
#pragma unroll
      for (int r = 0; r < 4; ++r) {
        float o1 = __shfl_xor(m1[i][r], m);
        float o2 = __shfl_xor(m2[i][r], m);
        int   oc = __shfl_xor(mcx[i][r], m);
        float hi = fmaxf(o1, m1[i][r]);
        m2[i][r] = fminf(fminf(m2[i][r], o2), hi);
        bool lt = o1 < m1[i][r];
        m1[i][r] = lt ? o1 : m1[i][r];
        mcx[i][r] = lt ? oc : mcx[i][r];
      }
  }
  if (c == 0) {
#pragma unroll
    for (int i = 0; i < 2; ++i)
#pragma unroll
      for (int r = 0; r < 4; ++r) {
        int query = qbase + i * 16 + q * 4 + r;
        idx[query] = mcx[i][r];
        if (m2[i][r] - m1[i][r] < TAU_S) { int p = atomicAdd(counter, 1); list[p] = query; }
      }
  }
}

// ---------------- refine: exact fp64 re-scan, lane-per-4-codes, 1 query/block ----------------
__global__ __launch_bounds__(256) void vq_refine(const float* __restrict__ x,
                                                 const float4* __restrict__ cbT4,
                                                 const double* __restrict__ c2d,
                                                 const int* __restrict__ list,
                                                 const int* __restrict__ counter,
                                                 int* __restrict__ idx) {
  __shared__ float xs[512];
  __shared__ double rv[4];
  __shared__ int rc[4];
  const int cnt = counter[0];
  const int tid = threadIdx.x, lane = tid & 63, wv = tid >> 6;
  for (int qi = blockIdx.x; qi < cnt; qi += gridDim.x) {
    const int query = list[qi];
    __syncthreads();
    xs[tid] = x[(size_t)query * KDIM + tid];
    xs[tid + 256] = x[(size_t)query * KDIM + tid + 256];
    __syncthreads();
    double a0 = 0, a1 = 0, a2 = 0, a3 = 0;
    const float4* xs4 = (const float4*)xs;
#pragma unroll 4
    for (int k4 = 0; k4 < 128; ++k4) {
      float4 xv = xs4[k4];
      float4 c0 = cbT4[(k4 * 4 + 0) * 256 + tid];
      float4 c1 = cbT4[(k4 * 4 + 1) * 256 + tid];
      float4 c2v = cbT4[(k4 * 4 + 2) * 256 + tid];
      float4 c3 = cbT4[(k4 * 4 + 3) * 256 + tid];
      a0 = fma((double)xv.x, (double)c0.x, a0);
      a1 = fma((double)xv.x, (double)c0.y, a1);
      a2 = fma((double)xv.x, (double)c0.z, a2);
      a3 = fma((double)xv.x, (double)c0.w, a3);
      a0 = fma((double)xv.y, (double)c1.x, a0);
      a1 = fma((double)xv.y, (double)c1.y, a1);
      a2 = fma((double)xv.y, (double)c1.z, a2);
      a3 = fma((double)xv.y, (double)c1.w, a3);
      a0 = fma((double)xv.z, (double)c2v.x, a0);
      a1 = fma((double)xv.z, (double)c2v.y, a1);
      a2 = fma((double)xv.z, (double)c2v.z, a2);
      a3 = fma((double)xv.z, (double)c2v.w, a3);
      a0 = fma((double)xv.w, (double)c3.x, a0);
      a1 = fma((double)xv.w, (double)c3.y, a1);
      a2 = fma((double)xv.w, (double)c3.z, a2);
      a3 = fma((double)xv.w, (double)c3.w, a3);
    }
    double best = c2d[tid * 4] - a0;
    int bc = tid * 4;
    double s1 = c2d[tid * 4 + 1] - a1;
    if (s1 < best) { best = s1; bc = tid * 4 + 1; }
    double s2 = c2d[tid * 4 + 2] - a2;
    if (s2 < best) { best = s2; bc = tid * 4 + 2; }
    double s3 = c2d[tid * 4 + 3] - a3;
    if (s3 < best) { best = s3; bc = tid * 4 + 3; }
#pragma unroll
    for (int m = 1; m < 64; m <<= 1) {
      double o = __shfl_xor(best, m);
      int oc = __shfl_xor(bc, m);
      if (o < best) { best = o; bc = oc; }
    }
    if (lane == 0) { rv[wv] = best; rc[wv] = bc; }
    __syncthreads();
    if (tid == 0) {
      double b = rv[0]; int bci = rc[0];
#pragma unroll
      for (int w = 1; w < 4; ++w)
        if (rv[w] < b) { b = rv[w]; bci = rc[w]; }
      idx[query] = bci;
    }
    __syncthreads();
  }
}

// ---------------- gather: out[q] = codebook[idx[q]] (grid-stride, NT stores) ----------------
__global__ __launch_bounds__(256) void vq_gather(const float* __restrict__ cb,
                                                 const int* __restrict__ idx,
                                                 float* __restrict__ out) {
  const size_t total = (size_t)NQ * 128;
  const size_t stride = (size_t)2048 * 256;
  size_t i = (size_t)blockIdx.x * 256 + threadIdx.x;
#pragma unroll 1
  for (; i < total; i += stride) {
    int qg = (int)(i >> 7), d = (int)(i & 127);
    const f32x4* src = (const f32x4*)(cb + (size_t)idx[qg] * KDIM + d * 4);
    f32x4 v = *src;
    __builtin_nontemporal_store(v, (f32x4*)(out + i * 4));
  }
}

extern "C" void kernel_launch(void* const* d_in, const int* in_sizes, int n_in,
                              void* d_out, int out_size, void* d_ws, size_t ws_size,
                              hipStream_t stream) {
  const float* x = (const float*)d_in[0];
  const float* cb = (const float*)d_in[1];
  float* out = (float*)d_out;
  char* ws = (char*)d_ws;
  if (ws_size < WS_NEED) {
    fprintf(stderr, "vq: ws_size %zu too small (need %llu)\n", ws_size,
            (unsigned long long)WS_NEED);
    return;
  }
  unsigned short* cbh = (unsigned short*)(ws + WS_CBH);
  float* c2h = (float*)(ws + WS_C2H);
  double* c2d = (double*)(ws + WS_C2D);
  float* cbT = (float*)(ws + WS_CBT);
  int* idx = (int*)(ws + WS_IDX);
  int* list = (int*)(ws + WS_LIST);
  int* counter = (int*)(ws + WS_CTR);

  hipMemsetAsync(counter, 0, 4, stream);
  vq_prep<<<384, 256, 0, stream>>>(cb, cbh, c2h, c2d, (float4*)cbT);
  vq_main<<<256, 512, 0, stream>>>(x, cbh, c2h, idx, list, counter);
  vq_refine<<<2048, 256, 0, stream>>>(x, (const float4*)cbT, c2d, list, counter, idx);
  vq_gather<<<2048, 256, 0, stream>>>(cb, idx, out);
}